// Round 1
// baseline (329.675 us; speedup 1.0000x reference)
//
#include <hip/hip_runtime.h>
#include <hip/hip_bf16.h>
#include <math.h>

// InteractionEncoder: B=32, N=64, D=256, ID=128, IN=516, H=256
// Key restructure: pair@W1 = A[b,i] + C[b,j] + geo@W1[512:516]
//   A = slots@W1[0:256]   (precomputed, d_ws)
//   C = slots@W1[256:512] (precomputed, d_ws)
// Main cost left: h[256]@W2[256,128] per pair (8.6 GFLOP, fp32 VALU-bound).

#define ROWS 2048          // B*N
#define HT_STRIDE 68       // 64 pairs + 4 pad (words) -> 16B-aligned float4 rows

#define ITY_OFF   16777216u
#define CAU_OFF   17825792u

// ---------------------------------------------------------------------------
// Kernel 1: A/C precompute.  256 blocks x 256 threads, 8 rows per block.
__global__ __launch_bounds__(256) void precomp_kernel(
    const float* __restrict__ slots,  // [2048][256]
    const float* __restrict__ W1,     // [516][256]
    float* __restrict__ Abuf,         // [2048][256]
    float* __restrict__ Cbuf)         // [2048][256]
{
  __shared__ __align__(16) float s[8][256];
  const int tid  = threadIdx.x;
  const int row0 = blockIdx.x * 8;
  #pragma unroll
  for (int r = 0; r < 8; ++r)
    s[r][tid] = slots[(row0 + r) * 256 + tid];
  __syncthreads();

  float accA[8] = {0.f,0.f,0.f,0.f,0.f,0.f,0.f,0.f};
  float accC[8] = {0.f,0.f,0.f,0.f,0.f,0.f,0.f,0.f};
  #pragma unroll 4
  for (int k = 0; k < 256; ++k) {
    const float wa = W1[k * 256 + tid];
    const float wc = W1[(256 + k) * 256 + tid];
    #pragma unroll
    for (int r = 0; r < 8; ++r) {
      accA[r] = fmaf(s[r][k], wa, accA[r]);
      accC[r] = fmaf(s[r][k], wc, accC[r]);
    }
  }
  #pragma unroll
  for (int r = 0; r < 8; ++r) {
    Abuf[(row0 + r) * 256 + tid] = accA[r];
    Cbuf[(row0 + r) * 256 + tid] = accC[r];
  }
}

// ---------------------------------------------------------------------------
// async global->LDS, 16B per lane.  LDS layout is linear in lane order
// (dst = base + tid*16 within each instruction) so the wave-uniform-base+
// lane*size hardware constraint is satisfied.
__device__ __forceinline__ void async_copy16(const float* gsrc, float* ldst) {
  __builtin_amdgcn_global_load_lds(
      (const __attribute__((address_space(1))) unsigned int*)gsrc,
      (__attribute__((address_space(3))) unsigned int*)ldst,
      16, 0, 0);
}

// ---------------------------------------------------------------------------
// Kernel 2: one block per (b,i).  64 pairs x (128 feats + itypes/causal).
__global__ __launch_bounds__(256, 1) void main_kernel(
    const float* __restrict__ positions, // [2048][4]
    const float* __restrict__ em,        // [2048]
    const float* __restrict__ W1,        // [516][256] (geo rows 512..515)
    const float* __restrict__ b1,        // [256]
    const float* __restrict__ W2,        // [256][128]
    const float* __restrict__ b2,        // [128]
    const float* __restrict__ Wt,        // [128][8]
    const float* __restrict__ bt,        // [8]
    const float* __restrict__ Wc,        // [128]
    const float* __restrict__ bc,        // [1]
    const float* __restrict__ Abuf,      // [2048][256]
    const float* __restrict__ Cbuf,      // [2048][256]
    float* __restrict__ out)
{
  __shared__ __align__(16) float HT[256 * HT_STRIDE];  // [k][j] hidden, padded
  __shared__ __align__(16) float W2b[2][64 * 128];     // K-chunk double buffer

  const int tid = threadIdx.x;
  // XCD swizzle: co-locate the 64 blocks sharing b on the same XCD (C-row L2 reuse)
  const int wid  = (blockIdx.x & 7) * 256 + (blockIdx.x >> 3);
  const int b    = wid >> 6;
  const int i    = wid & 63;
  const int rowi = b * 64 + i;

  // kick off W2 chunk 0 load (overlaps H-build)
  {
    const float* g = W2 + tid * 4;
    float* l = &W2b[0][tid * 4];
    #pragma unroll
    for (int q = 0; q < 8; ++q) async_copy16(g + q * 1024, l + q * 1024);
  }

  // ---- H build: thread owns hidden index k = tid for all 64 j ----
  {
    const int k = tid;
    const float g0 = W1[512 * 256 + k];
    const float g1 = W1[513 * 256 + k];
    const float g2 = W1[514 * 256 + k];
    const float g3 = W1[515 * 256 + k];
    const float base = Abuf[rowi * 256 + k] + b1[k];
    const float pxi = positions[rowi * 4 + 0];
    const float pyi = positions[rowi * 4 + 1];

    #pragma unroll 2
    for (int jg = 0; jg < 16; ++jg) {
      float hh[4];
      #pragma unroll
      for (int c = 0; c < 4; ++c) {
        const int j    = jg * 4 + c;
        const int rowj = b * 64 + j;
        const float cv = Cbuf[rowj * 256 + k];            // coalesced per instr
        const float rx = pxi - positions[rowj * 4 + 0];
        const float ry = pyi - positions[rowj * 4 + 1];
        const float d2 = rx * rx + ry * ry;
        const float dist = (d2 == 0.f) ? 0.f : sqrtf(d2);
        const float dn   = dist * (1.0f / 50.0f);
        const float dncl = fminf(dn, 1.0f);
        float h = base + cv + rx * g0 + ry * g1 + dn * g2 + dncl * g3;
        hh[c] = fmaxf(h, 0.f);
      }
      float4 hv = make_float4(hh[0], hh[1], hh[2], hh[3]);
      *(float4*)&HT[k * HT_STRIDE + jg * 4] = hv;
    }
  }

  const int fg = tid & 15;   // feat group: d = fg*8 .. +7
  const int pg = tid >> 4;   // pair group: j = pg*4 .. +3

  float acc[4][8];
  #pragma unroll
  for (int p = 0; p < 4; ++p)
    #pragma unroll
    for (int d = 0; d < 8; ++d) acc[p][d] = 0.f;

  __syncthreads();  // HT ready + W2 chunk0 landed (barrier drains vmcnt)

  // ---- GEMM: out[64 pairs][128 feats] = HT^T @ W2, K chunked by 64 ----
  #pragma unroll
  for (int ch = 0; ch < 4; ++ch) {
    if (ch < 3) {  // prefetch next chunk into other buffer, in flight across GEMM
      const float* g = W2 + (ch + 1) * 8192 + tid * 4;
      float* l = &W2b[(ch + 1) & 1][tid * 4];
      #pragma unroll
      for (int q = 0; q < 8; ++q) async_copy16(g + q * 1024, l + q * 1024);
    }
    const float* w2c = &W2b[ch & 1][0];
    #pragma unroll 4
    for (int kk = 0; kk < 64; ++kk) {
      const float4 h4 = *(const float4*)&HT[(ch * 64 + kk) * HT_STRIDE + pg * 4];
      const float4 wa = *(const float4*)&w2c[kk * 128 + fg * 8];
      const float4 wb = *(const float4*)&w2c[kk * 128 + fg * 8 + 4];
      const float hv[4] = {h4.x, h4.y, h4.z, h4.w};
      const float wv[8] = {wa.x, wa.y, wa.z, wa.w, wb.x, wb.y, wb.z, wb.w};
      #pragma unroll
      for (int p = 0; p < 4; ++p) {
        #pragma unroll
        for (int d = 0; d < 8; ++d)
          acc[p][d] = fmaf(hv[p], wv[d], acc[p][d]);
      }
    }
    __syncthreads();  // done reading this buffer; next-chunk loads drained
  }

  // ---- epilogue: bias + mask, store feats; itypes/causal via shfl reduce ----
  float wtv[8][8], wcv[8], b2v[8], btq[8];
  #pragma unroll
  for (int d = 0; d < 8; ++d) {
    const int dd = fg * 8 + d;
    const float4 a = *(const float4*)&Wt[dd * 8 + 0];
    const float4 c = *(const float4*)&Wt[dd * 8 + 4];
    wtv[d][0] = a.x; wtv[d][1] = a.y; wtv[d][2] = a.z; wtv[d][3] = a.w;
    wtv[d][4] = c.x; wtv[d][5] = c.y; wtv[d][6] = c.z; wtv[d][7] = c.w;
    wcv[d] = Wc[dd];
  }
  {
    const float4 x = *(const float4*)&b2[fg * 8];
    const float4 y = *(const float4*)&b2[fg * 8 + 4];
    b2v[0]=x.x; b2v[1]=x.y; b2v[2]=x.z; b2v[3]=x.w;
    b2v[4]=y.x; b2v[5]=y.y; b2v[6]=y.z; b2v[7]=y.w;
  }
  {
    const float4 x = *(const float4*)&bt[0];
    const float4 y = *(const float4*)&bt[4];
    btq[0]=x.x; btq[1]=x.y; btq[2]=x.z; btq[3]=x.w;
    btq[4]=y.x; btq[5]=y.y; btq[6]=y.z; btq[7]=y.w;
  }
  const float bcv = bc[0];
  const float emi = em[rowi];

  #pragma unroll
  for (int p = 0; p < 4; ++p) {
    const int j    = pg * 4 + p;
    const int rowj = b * 64 + j;
    const float mask = emi * em[rowj];

    float f[8];
    #pragma unroll
    for (int d = 0; d < 8; ++d) f[d] = (acc[p][d] + b2v[d]) * mask;

    const size_t fo = ((size_t)rowi * 64 + j) * 128 + fg * 8;
    *(float4*)&out[fo]     = make_float4(f[0], f[1], f[2], f[3]);
    *(float4*)&out[fo + 4] = make_float4(f[4], f[5], f[6], f[7]);

    // partial dot with Wt/Wc over this thread's 8 feats
    float t[9];
    #pragma unroll
    for (int q = 0; q < 9; ++q) t[q] = 0.f;
    #pragma unroll
    for (int d = 0; d < 8; ++d) {
      #pragma unroll
      for (int q = 0; q < 8; ++q) t[q] = fmaf(f[d], wtv[d][q], t[q]);
      t[8] = fmaf(f[d], wcv[d], t[8]);
    }
    // reduce across the 16 fg lanes (fg == lane&15 since waves are 16-aligned)
    #pragma unroll
    for (int m = 1; m < 16; m <<= 1) {
      #pragma unroll
      for (int q = 0; q < 9; ++q) t[q] += __shfl_xor(t[q], m, 64);
    }
    if (fg == 0) {
      const size_t io = (size_t)ITY_OFF + ((size_t)rowi * 64 + j) * 8;
      *(float4*)&out[io]     = make_float4(t[0] + btq[0], t[1] + btq[1],
                                           t[2] + btq[2], t[3] + btq[3]);
      *(float4*)&out[io + 4] = make_float4(t[4] + btq[4], t[5] + btq[5],
                                           t[6] + btq[6], t[7] + btq[7]);
      const float cz = t[8] + bcv;
      out[(size_t)CAU_OFF + (size_t)rowi * 64 + j] = mask / (1.f + expf(-cz));
    }
  }
}

// ---------------------------------------------------------------------------
extern "C" void kernel_launch(void* const* d_in, const int* in_sizes, int n_in,
                              void* d_out, int out_size, void* d_ws, size_t ws_size,
                              hipStream_t stream) {
  const float* slots     = (const float*)d_in[0];
  const float* positions = (const float*)d_in[1];
  const float* em        = (const float*)d_in[2];
  const float* W1        = (const float*)d_in[3];
  const float* b1        = (const float*)d_in[4];
  const float* W2        = (const float*)d_in[5];
  const float* b2        = (const float*)d_in[6];
  const float* Wt        = (const float*)d_in[7];
  const float* bt        = (const float*)d_in[8];
  const float* Wc        = (const float*)d_in[9];
  const float* bc        = (const float*)d_in[10];
  float* out  = (float*)d_out;
  float* Abuf = (float*)d_ws;                  // [2048][256]
  float* Cbuf = Abuf + (size_t)ROWS * 256;     // [2048][256]  (4 MB total)

  precomp_kernel<<<256, 256, 0, stream>>>(slots, W1, Abuf, Cbuf);
  main_kernel<<<2048, 256, 0, stream>>>(positions, em, W1, b1, W2, b2,
                                        Wt, bt, Wc, bc, Abuf, Cbuf, out);
}

// Round 2
// 242.451 us; speedup vs baseline: 1.3598x; 1.3598x over previous
//
#include <hip/hip_runtime.h>
#include <hip/hip_bf16.h>
#include <math.h>

// InteractionEncoder: B=32, N=64, D=256, ID=128, IN=516, H=256
// pair@W1 = A[b,i] + C[b,j] + geo(i,j)@W1[512:516]  (A,C precomputed in d_ws)
// Main cost: h[256]@W2[256,128] per pair, fp32 VALU.
// R2: K-chunked HT (32-k chunks, double-buffered) -> LDS 48KB -> 3 blocks/CU.

#define ROWS 2048
#define ITY_OFF   16777216u   // 2048*64*128
#define CAU_OFF   17825792u   // + 2048*64*8

// ---------------------------------------------------------------------------
// Kernel 1: A/C precompute.  256 blocks x 256 threads, 8 rows per block.
__global__ __launch_bounds__(256) void precomp_kernel(
    const float* __restrict__ slots,  // [2048][256]
    const float* __restrict__ W1,     // [516][256]
    float* __restrict__ Abuf,         // [2048][256]
    float* __restrict__ Cbuf)         // [2048][256]
{
  __shared__ __align__(16) float s[8][256];
  const int tid  = threadIdx.x;
  const int row0 = blockIdx.x * 8;
  #pragma unroll
  for (int r = 0; r < 8; ++r)
    s[r][tid] = slots[(row0 + r) * 256 + tid];
  __syncthreads();

  float accA[8] = {0.f,0.f,0.f,0.f,0.f,0.f,0.f,0.f};
  float accC[8] = {0.f,0.f,0.f,0.f,0.f,0.f,0.f,0.f};
  #pragma unroll 4
  for (int k = 0; k < 256; ++k) {
    const float wa = W1[k * 256 + tid];
    const float wc = W1[(256 + k) * 256 + tid];
    #pragma unroll
    for (int r = 0; r < 8; ++r) {
      accA[r] = fmaf(s[r][k], wa, accA[r]);
      accC[r] = fmaf(s[r][k], wc, accC[r]);
    }
  }
  #pragma unroll
  for (int r = 0; r < 8; ++r) {
    Abuf[(row0 + r) * 256 + tid] = accA[r];
    Cbuf[(row0 + r) * 256 + tid] = accC[r];
  }
}

// ---------------------------------------------------------------------------
__device__ __forceinline__ void async_copy16(const float* gsrc, float* ldst) {
  __builtin_amdgcn_global_load_lds(
      (const __attribute__((address_space(1))) unsigned int*)gsrc,
      (__attribute__((address_space(3))) unsigned int*)ldst,
      16, 0, 0);
}

// ---------------------------------------------------------------------------
// Kernel 2: one block per (b,i).  LDS = 2*8KB (HT chunks) + 2*16KB (W2 chunks).
__global__ __launch_bounds__(256, 3) void main_kernel(
    const float* __restrict__ positions, // [2048][4]
    const float* __restrict__ em,        // [2048]
    const float* __restrict__ W1,        // [516][256] (geo rows 512..515)
    const float* __restrict__ b1,        // [256]
    const float* __restrict__ W2,        // [256][128]
    const float* __restrict__ b2,        // [128]
    const float* __restrict__ Wt,        // [128][8]
    const float* __restrict__ bt,        // [8]
    const float* __restrict__ Wc,        // [128]
    const float* __restrict__ bc,        // [1]
    const float* __restrict__ Abuf,      // [2048][256]
    const float* __restrict__ Cbuf,      // [2048][256]
    float* __restrict__ out)
{
  __shared__ __align__(16) float HTc[2][32 * 64];   // [k][j], XOR-swizzled, 2x8KB
  __shared__ __align__(16) float W2c[2][32 * 128];  // [k][d], linear, 2x16KB

  const int tid = threadIdx.x;
  // XCD swizzle: the 64 blocks sharing b land on one XCD (C/A tile L2 reuse)
  const int wid  = (blockIdx.x & 7) * 256 + (blockIdx.x >> 3);
  const int b    = wid >> 6;
  const int i    = wid & 63;
  const int rowi = b * 64 + i;

  const int fg  = tid & 15;      // feat group: d = fg*8 .. +7
  const int pg  = tid >> 4;      // pair group: j = pg*4 .. +3  (pg 0..15)
  const int pg4 = pg * 4;

  const int kl  = tid & 31;      // H-build: local k within chunk
  const int j0  = (tid >> 5) * 8; // H-build: this thread's 8 j values

  // ---- per-thread loop-invariant geometry for j = j0..j0+7 ----
  float grx[8], gry[8], gdn[8], gdc[8];
  {
    const float pxi = positions[rowi * 4 + 0];
    const float pyi = positions[rowi * 4 + 1];
    #pragma unroll
    for (int jj = 0; jj < 8; ++jj) {
      const int rowj = b * 64 + j0 + jj;
      const float rx = pxi - positions[rowj * 4 + 0];
      const float ry = pyi - positions[rowj * 4 + 1];
      const float d2 = rx * rx + ry * ry;
      const float dist = (d2 == 0.f) ? 0.f : sqrtf(d2);
      const float dn = dist * (1.0f / 50.0f);
      grx[jj] = rx; gry[jj] = ry; gdn[jj] = dn; gdc[jj] = fminf(dn, 1.0f);
    }
  }

  float acc[4][8];
  #pragma unroll
  for (int p = 0; p < 4; ++p)
    #pragma unroll
    for (int d = 0; d < 8; ++d) acc[p][d] = 0.f;

  // ---- prologue: stage W2 chunk 0 (async) + build HT chunk 0 ----
  {
    const float* g = W2 + tid * 4;
    float* l = &W2c[0][tid * 4];
    #pragma unroll
    for (int q = 0; q < 4; ++q) async_copy16(g + q * 1024, l + q * 1024);
  }
  {
    const int k = kl;  // chunk 0
    const float base = Abuf[rowi * 256 + k] + b1[k];
    const float g0 = W1[512 * 256 + k];
    const float g1 = W1[513 * 256 + k];
    const float g2 = W1[514 * 256 + k];
    const float g3 = W1[515 * 256 + k];
    float* Hrow = &HTc[0][kl * 64];
    #pragma unroll
    for (int q = 0; q < 2; ++q) {
      float hh[4];
      #pragma unroll
      for (int c = 0; c < 4; ++c) {
        const int jj = q * 4 + c;
        const float cv = Cbuf[(b * 64 + j0 + jj) * 256 + k];
        float h = base + cv + grx[jj] * g0 + gry[jj] * g1
                          + gdn[jj] * g2 + gdc[jj] * g3;
        hh[c] = fmaxf(h, 0.f);
      }
      const int w = (j0 + q * 4) ^ ((kl & 7) << 2);  // bank swizzle
      *(float4*)&Hrow[w] = make_float4(hh[0], hh[1], hh[2], hh[3]);
    }
  }
  __syncthreads();

  // ---- main loop over 8 K-chunks of 32 ----
  #pragma unroll 1
  for (int kc = 0; kc < 8; ++kc) {
    const int cur = kc & 1;

    if (kc < 7) {
      // stage W2 chunk kc+1 (async, in flight across the GEMM below)
      {
        const float* g = W2 + (kc + 1) * 4096 + tid * 4;
        float* l = &W2c[cur ^ 1][tid * 4];
        #pragma unroll
        for (int q = 0; q < 4; ++q) async_copy16(g + q * 1024, l + q * 1024);
      }
      // build HT chunk kc+1 into the other buffer (loads hide under GEMM)
      {
        const int k = (kc + 1) * 32 + kl;
        const float base = Abuf[rowi * 256 + k] + b1[k];
        const float g0 = W1[512 * 256 + k];
        const float g1 = W1[513 * 256 + k];
        const float g2 = W1[514 * 256 + k];
        const float g3 = W1[515 * 256 + k];
        float* Hrow = &HTc[cur ^ 1][kl * 64];
        #pragma unroll
        for (int q = 0; q < 2; ++q) {
          float hh[4];
          #pragma unroll
          for (int c = 0; c < 4; ++c) {
            const int jj = q * 4 + c;
            const float cv = Cbuf[(b * 64 + j0 + jj) * 256 + k];
            float h = base + cv + grx[jj] * g0 + gry[jj] * g1
                              + gdn[jj] * g2 + gdc[jj] * g3;
            hh[c] = fmaxf(h, 0.f);
          }
          const int w = (j0 + q * 4) ^ ((kl & 7) << 2);
          *(float4*)&Hrow[w] = make_float4(hh[0], hh[1], hh[2], hh[3]);
        }
      }
    }

    // GEMM over this chunk's 32 k
    const float* Hb = &HTc[cur][0];
    const float* Wb = &W2c[cur][0];
    #pragma unroll 8
    for (int kk = 0; kk < 32; ++kk) {
      const float4 h4 = *(const float4*)&Hb[kk * 64 + (pg4 ^ ((kk & 7) << 2))];
      const float4 wa = *(const float4*)&Wb[kk * 128 + fg * 8];
      const float4 wb = *(const float4*)&Wb[kk * 128 + fg * 8 + 4];
      const float hv[4] = {h4.x, h4.y, h4.z, h4.w};
      const float wv[8] = {wa.x, wa.y, wa.z, wa.w, wb.x, wb.y, wb.z, wb.w};
      #pragma unroll
      for (int p = 0; p < 4; ++p)
        #pragma unroll
        for (int d = 0; d < 8; ++d)
          acc[p][d] = fmaf(hv[p], wv[d], acc[p][d]);
    }
    __syncthreads();
  }

  // ---- epilogue: bias + mask, store feats; itypes/causal via shfl reduce ----
  float wtv[8][8], wcv[8], b2v[8], btq[8];
  #pragma unroll
  for (int d = 0; d < 8; ++d) {
    const int dd = fg * 8 + d;
    const float4 a = *(const float4*)&Wt[dd * 8 + 0];
    const float4 c = *(const float4*)&Wt[dd * 8 + 4];
    wtv[d][0] = a.x; wtv[d][1] = a.y; wtv[d][2] = a.z; wtv[d][3] = a.w;
    wtv[d][4] = c.x; wtv[d][5] = c.y; wtv[d][6] = c.z; wtv[d][7] = c.w;
    wcv[d] = Wc[dd];
  }
  {
    const float4 x = *(const float4*)&b2[fg * 8];
    const float4 y = *(const float4*)&b2[fg * 8 + 4];
    b2v[0]=x.x; b2v[1]=x.y; b2v[2]=x.z; b2v[3]=x.w;
    b2v[4]=y.x; b2v[5]=y.y; b2v[6]=y.z; b2v[7]=y.w;
  }
  {
    const float4 x = *(const float4*)&bt[0];
    const float4 y = *(const float4*)&bt[4];
    btq[0]=x.x; btq[1]=x.y; btq[2]=x.z; btq[3]=x.w;
    btq[4]=y.x; btq[5]=y.y; btq[6]=y.z; btq[7]=y.w;
  }
  const float bcv = bc[0];
  const float emi = em[rowi];

  #pragma unroll
  for (int p = 0; p < 4; ++p) {
    const int j    = pg4 + p;
    const int rowj = b * 64 + j;
    const float mask = emi * em[rowj];

    float f[8];
    #pragma unroll
    for (int d = 0; d < 8; ++d) f[d] = (acc[p][d] + b2v[d]) * mask;

    const size_t fo = ((size_t)rowi * 64 + j) * 128 + fg * 8;
    *(float4*)&out[fo]     = make_float4(f[0], f[1], f[2], f[3]);
    *(float4*)&out[fo + 4] = make_float4(f[4], f[5], f[6], f[7]);

    float t[9];
    #pragma unroll
    for (int q = 0; q < 9; ++q) t[q] = 0.f;
    #pragma unroll
    for (int d = 0; d < 8; ++d) {
      #pragma unroll
      for (int q = 0; q < 8; ++q) t[q] = fmaf(f[d], wtv[d][q], t[q]);
      t[8] = fmaf(f[d], wcv[d], t[8]);
    }
    #pragma unroll
    for (int m = 1; m < 16; m <<= 1) {
      #pragma unroll
      for (int q = 0; q < 9; ++q) t[q] += __shfl_xor(t[q], m, 64);
    }
    if (fg == 0) {
      const size_t io = (size_t)ITY_OFF + ((size_t)rowi * 64 + j) * 8;
      *(float4*)&out[io]     = make_float4(t[0] + btq[0], t[1] + btq[1],
                                           t[2] + btq[2], t[3] + btq[3]);
      *(float4*)&out[io + 4] = make_float4(t[4] + btq[4], t[5] + btq[5],
                                           t[6] + btq[6], t[7] + btq[7]);
      const float cz = t[8] + bcv;
      out[(size_t)CAU_OFF + (size_t)rowi * 64 + j] = mask / (1.f + expf(-cz));
    }
  }
}

// ---------------------------------------------------------------------------
extern "C" void kernel_launch(void* const* d_in, const int* in_sizes, int n_in,
                              void* d_out, int out_size, void* d_ws, size_t ws_size,
                              hipStream_t stream) {
  const float* slots     = (const float*)d_in[0];
  const float* positions = (const float*)d_in[1];
  const float* em        = (const float*)d_in[2];
  const float* W1        = (const float*)d_in[3];
  const float* b1        = (const float*)d_in[4];
  const float* W2        = (const float*)d_in[5];
  const float* b2        = (const float*)d_in[6];
  const float* Wt        = (const float*)d_in[7];
  const float* bt        = (const float*)d_in[8];
  const float* Wc        = (const float*)d_in[9];
  const float* bc        = (const float*)d_in[10];
  float* out  = (float*)d_out;
  float* Abuf = (float*)d_ws;                  // [2048][256]
  float* Cbuf = Abuf + (size_t)ROWS * 256;     // [2048][256]

  precomp_kernel<<<256, 256, 0, stream>>>(slots, W1, Abuf, Cbuf);
  main_kernel<<<2048, 256, 0, stream>>>(positions, em, W1, b1, W2, b2,
                                        Wt, bt, Wc, bc, Abuf, Cbuf, out);
}

// Round 3
// 221.405 us; speedup vs baseline: 1.4890x; 1.0951x over previous
//
#include <hip/hip_runtime.h>
#include <hip/hip_bf16.h>
#include <math.h>

// InteractionEncoder: B=32, N=64, D=256, ID=128, IN=516, H=256
// pair@W1 = A[b,i] + C[b,j] + geo(i,j)@W1[512:516]  (A,C precomputed, b1 folded into A)
// Layer 2 as MFMA bf16 hi/lo split (3-term) GEMM: H[64x256] @ W2ext[256x144],
// where cols 128-135 = W2@Wt (itypes), col 136 = W2@Wc (causal), 137-143 = 0 pad.
// W2ext pre-split + pre-packed into 16x16x32 B-fragment order in d_ws.

typedef __attribute__((ext_vector_type(8))) short  bfrag8;  // 8 bf16 (bits)
typedef __attribute__((ext_vector_type(4))) short  spack4;  // 4 bf16 (bits)
typedef __attribute__((ext_vector_type(4))) float  fvec4;

#define ITY_OFF   16777216u   // 2048*64*128
#define CAU_OFF   17825792u   // + 2048*64*8

static __device__ __forceinline__ short f2bf(float f) {   // RNE f32->bf16 bits
  unsigned u = __float_as_uint(f);
  u = u + 0x7FFF + ((u >> 16) & 1);
  return (short)(u >> 16);
}
static __device__ __forceinline__ float bf2f(short s) {
  return __uint_as_float(((unsigned)(unsigned short)s) << 16);
}

// ---------------------------------------------------------------------------
// P1: pack W2ext (144 cols: W2 | W2@Wt | W2@Wc | pad) as hi/lo bf16 B-fragments.
// Fragment (ks,db): lane l holds 8 elems: k = ks*32+(l>>4)*8+e, d = db*16+(l&15).
// 72 tiles x 64 lanes; grid 18 x 256.
__global__ __launch_bounds__(256) void prep_w(
    const float* __restrict__ W2,   // [256][128]
    const float* __restrict__ b2,   // [128]
    const float* __restrict__ Wt,   // [128][8]
    const float* __restrict__ Wc,   // [128]
    float* __restrict__ b2e,        // [144]
    short* __restrict__ WfHi,       // [72][64][8]
    short* __restrict__ WfLo)
{
  const int tid  = threadIdx.x;
  const int tile = blockIdx.x * 4 + (tid >> 6);
  const int l    = tid & 63;
  const int ks   = tile / 9, db = tile - ks * 9;
  const int d    = db * 16 + (l & 15);
  const int k0   = ks * 32 + ((l >> 4) & 3) * 8;

  float v[8];
  if (d < 128) {
    #pragma unroll
    for (int e = 0; e < 8; ++e) v[e] = W2[(k0 + e) * 128 + d];
  } else if (d < 137) {
    const int q = d - 128;
    #pragma unroll
    for (int e = 0; e < 8; ++e) {
      float s = 0.f;
      for (int c = 0; c < 128; ++c)
        s = fmaf(W2[(k0 + e) * 128 + c], (q < 8) ? Wt[c * 8 + q] : Wc[c], s);
      v[e] = s;
    }
  } else {
    #pragma unroll
    for (int e = 0; e < 8; ++e) v[e] = 0.f;
  }

  bfrag8 hi, lo;
  #pragma unroll
  for (int e = 0; e < 8; ++e) {
    const short hb = f2bf(v[e]);
    hi[e] = hb;
    lo[e] = f2bf(v[e] - bf2f(hb));
  }
  *(bfrag8*)&WfHi[(tile * 64 + l) * 8] = hi;
  *(bfrag8*)&WfLo[(tile * 64 + l) * 8] = lo;

  if (blockIdx.x == 17 && tid < 144) {   // b2e: b2 | b2@Wt | b2@Wc | 0
    float s = 0.f;
    if (tid < 128) s = b2[tid];
    else if (tid < 137) {
      const int q = tid - 128;
      for (int c = 0; c < 128; ++c)
        s = fmaf(b2[c], (q < 8) ? Wt[c * 8 + q] : Wc[c], s);
    }
    b2e[tid] = s;
  }
}

// ---------------------------------------------------------------------------
// P2: A/C precompute. 512 blocks x 256 thr, 4 rows/block, 1 col pair/thread.
__global__ __launch_bounds__(256) void prep_ac(
    const float* __restrict__ slots,  // [2048][256]
    const float* __restrict__ W1,     // [516][256]
    const float* __restrict__ b1,     // [256]
    float* __restrict__ Abuf,         // [2048][256] = slots@W1[0:256] + b1
    float* __restrict__ Cbuf)         // [2048][256] = slots@W1[256:512]
{
  __shared__ __align__(16) float s[4][256];
  const int tid  = threadIdx.x;
  const int row0 = blockIdx.x * 4;
  {
    const int r = tid >> 6, o = (tid & 63) * 4;
    *(fvec4*)&s[r][o] = *(const fvec4*)&slots[(row0 + r) * 256 + o];
  }
  __syncthreads();

  float accA[4] = {0.f, 0.f, 0.f, 0.f};
  float accC[4] = {0.f, 0.f, 0.f, 0.f};
  #pragma unroll 2
  for (int k4 = 0; k4 < 64; ++k4) {
    fvec4 sv[4];
    #pragma unroll
    for (int r = 0; r < 4; ++r) sv[r] = *(const fvec4*)&s[r][k4 * 4];
    #pragma unroll
    for (int e = 0; e < 4; ++e) {
      const int k = k4 * 4 + e;
      const float wa = W1[k * 256 + tid];
      const float wc = W1[(256 + k) * 256 + tid];
      #pragma unroll
      for (int r = 0; r < 4; ++r) {
        accA[r] = fmaf(sv[r][e], wa, accA[r]);
        accC[r] = fmaf(sv[r][e], wc, accC[r]);
      }
    }
  }
  const float bv = b1[tid];
  #pragma unroll
  for (int r = 0; r < 4; ++r) {
    Abuf[(row0 + r) * 256 + tid] = accA[r] + bv;
    Cbuf[(row0 + r) * 256 + tid] = accC[r];
  }
}

// ---------------------------------------------------------------------------
// Main: one block per (b,i). Phase1 builds H (bf16 hi/lo, XOR-swizzled LDS),
// Phase2 MFMA 16x16x32 (3-term split), Phase3 per-lane epilogue.
__global__ __launch_bounds__(256, 2) void main_kernel(
    const float* __restrict__ positions, // [2048][4]
    const float* __restrict__ em,        // [2048]
    const float* __restrict__ W1,        // [516][256] (geo rows 512..515)
    const float* __restrict__ Abuf,
    const float* __restrict__ Cbuf,
    const float* __restrict__ b2e,       // [144]
    const short* __restrict__ WfHi,      // B-fragments hi
    const short* __restrict__ WfLo,      // B-fragments lo
    const float* __restrict__ bt,        // [8]
    const float* __restrict__ bc,        // [1]
    float* __restrict__ out)
{
  __shared__ __align__(16) short Hhi_s[64 * 256];  // [j][k] bf16 hi, 32KB
  __shared__ __align__(16) short Hlo_s[64 * 256];  // lo, 32KB
  __shared__ float maskL[64];

  const int tid = threadIdx.x;
  const int l   = tid & 63;
  const int w   = tid >> 6;
  // XCD swizzle: 64 blocks sharing b land on one XCD (Cbuf slice L2 reuse)
  const int wid  = (blockIdx.x & 7) * 256 + (blockIdx.x >> 3);
  const int b    = wid >> 6;
  const int i    = wid & 63;
  const int rowi = b * 64 + i;

  if (tid < 64) maskL[tid] = em[rowi] * em[b * 64 + tid];

  char* HhiB = (char*)Hhi_s;
  char* HloB = (char*)Hlo_s;

  // ---- phase 1: H build. thread: 4 j values (w*16+jj*4+jsub), k = kb*64+(l&15)*4 ----
  {
    const int jsub = l >> 4;
    const int kl4  = (l & 15) * 4;
    const float pxi = positions[rowi * 4 + 0];
    const float pyi = positions[rowi * 4 + 1];
    float grx[4], gry[4], gdn[4], gdc[4];
    #pragma unroll
    for (int jj = 0; jj < 4; ++jj) {
      const int rowj = b * 64 + w * 16 + jj * 4 + jsub;
      const float rx = pxi - positions[rowj * 4 + 0];
      const float ry = pyi - positions[rowj * 4 + 1];
      const float d2 = rx * rx + ry * ry;
      const float dist = (d2 == 0.f) ? 0.f : sqrtf(d2);
      const float dn = dist * (1.0f / 50.0f);
      grx[jj] = rx; gry[jj] = ry; gdn[jj] = dn; gdc[jj] = fminf(dn, 1.f);
    }
    #pragma unroll 1
    for (int kb = 0; kb < 4; ++kb) {
      const int k = kb * 64 + kl4;
      const fvec4 a4 = *(const fvec4*)&Abuf[rowi * 256 + k];   // A + b1
      const fvec4 g0 = *(const fvec4*)&W1[512 * 256 + k];
      const fvec4 g1 = *(const fvec4*)&W1[513 * 256 + k];
      const fvec4 g2 = *(const fvec4*)&W1[514 * 256 + k];
      const fvec4 g3 = *(const fvec4*)&W1[515 * 256 + k];
      #pragma unroll
      for (int jj = 0; jj < 4; ++jj) {
        const int j = w * 16 + jj * 4 + jsub;
        const fvec4 c4 = *(const fvec4*)&Cbuf[(b * 64 + j) * 256 + k];
        spack4 hi, lo;
        #pragma unroll
        for (int e = 0; e < 4; ++e) {
          float h = a4[e] + c4[e] + grx[jj] * g0[e] + gry[jj] * g1[e]
                  + gdn[jj] * g2[e] + gdc[jj] * g3[e];
          h = fmaxf(h, 0.f);
          const short hb = f2bf(h);
          hi[e] = hb;
          lo[e] = f2bf(h - bf2f(hb));
        }
        // full-address XOR swizzle (consistent with phase-2 reads)
        const int byte = (j * 512 + k * 2) ^ ((j & 7) << 4);
        *(spack4*)(HhiB + byte) = hi;
        *(spack4*)(HloB + byte) = lo;
      }
    }
  }
  __syncthreads();

  // ---- phase 2: MFMA GEMM. wave w: dblocks {2w,2w+1} (+ db 8 for w==3) ----
  const int laneJ = l & 15;
  const int laneK = l >> 4;
  const int addrA = laneJ * 512 + laneK * 16;
  const int swzA  = (laneJ & 7) << 4;

  fvec4 acc[4][3];
  #pragma unroll
  for (int jb = 0; jb < 4; ++jb) {
    acc[jb][0] = 0.f; acc[jb][1] = 0.f; acc[jb][2] = 0.f;
  }

  const int db0 = w * 2, db1 = w * 2 + 1;
  #pragma unroll
  for (int ks = 0; ks < 8; ++ks) {
    bfrag8 bh0 = *(const bfrag8*)&WfHi[((ks * 9 + db0) * 64 + l) * 8];
    bfrag8 bl0 = *(const bfrag8*)&WfLo[((ks * 9 + db0) * 64 + l) * 8];
    bfrag8 bh1 = *(const bfrag8*)&WfHi[((ks * 9 + db1) * 64 + l) * 8];
    bfrag8 bl1 = *(const bfrag8*)&WfLo[((ks * 9 + db1) * 64 + l) * 8];
    bfrag8 bh2 = {}, bl2 = {};
    if (w == 3) {
      bh2 = *(const bfrag8*)&WfHi[((ks * 9 + 8) * 64 + l) * 8];
      bl2 = *(const bfrag8*)&WfLo[((ks * 9 + 8) * 64 + l) * 8];
    }
    #pragma unroll
    for (int jb = 0; jb < 4; ++jb) {
      const int base = addrA + jb * 8192 + ks * 64;
      const bfrag8 ah = *(const bfrag8*)(HhiB + (base ^ swzA));
      const bfrag8 al = *(const bfrag8*)(HloB + (base ^ swzA));
      acc[jb][0] = __builtin_amdgcn_mfma_f32_16x16x32_bf16(ah, bh0, acc[jb][0], 0, 0, 0);
      acc[jb][0] = __builtin_amdgcn_mfma_f32_16x16x32_bf16(ah, bl0, acc[jb][0], 0, 0, 0);
      acc[jb][0] = __builtin_amdgcn_mfma_f32_16x16x32_bf16(al, bh0, acc[jb][0], 0, 0, 0);
      acc[jb][1] = __builtin_amdgcn_mfma_f32_16x16x32_bf16(ah, bh1, acc[jb][1], 0, 0, 0);
      acc[jb][1] = __builtin_amdgcn_mfma_f32_16x16x32_bf16(ah, bl1, acc[jb][1], 0, 0, 0);
      acc[jb][1] = __builtin_amdgcn_mfma_f32_16x16x32_bf16(al, bh1, acc[jb][1], 0, 0, 0);
      if (w == 3) {
        acc[jb][2] = __builtin_amdgcn_mfma_f32_16x16x32_bf16(ah, bh2, acc[jb][2], 0, 0, 0);
        acc[jb][2] = __builtin_amdgcn_mfma_f32_16x16x32_bf16(ah, bl2, acc[jb][2], 0, 0, 0);
        acc[jb][2] = __builtin_amdgcn_mfma_f32_16x16x32_bf16(al, bh2, acc[jb][2], 0, 0, 0);
      }
    }
  }

  // ---- phase 3: epilogue (C/D: col = laneJ, row = laneK*4 + r) ----
  #pragma unroll
  for (int t = 0; t < 2; ++t) {
    const int d = (w * 2 + t) * 16 + laneJ;
    const float bv = b2e[d];
    #pragma unroll
    for (int jb = 0; jb < 4; ++jb) {
      #pragma unroll
      for (int r = 0; r < 4; ++r) {
        const int j = jb * 16 + laneK * 4 + r;
        const float m = maskL[j];
        out[((size_t)(rowi * 64 + j)) * 128 + d] = (acc[jb][t][r] + bv) * m;
      }
    }
  }
  if (w == 3) {
    const int d = 128 + laneJ;
    const float bv = b2e[d];
    const float btv = (laneJ < 8) ? bt[laneJ] : 0.f;
    const float bcv = bc[0];
    #pragma unroll
    for (int jb = 0; jb < 4; ++jb) {
      #pragma unroll
      for (int r = 0; r < 4; ++r) {
        const int j = jb * 16 + laneK * 4 + r;
        const float m = maskL[j];
        const float val = (acc[jb][2][r] + bv) * m;
        if (laneJ < 8) {
          out[(size_t)ITY_OFF + (size_t)(rowi * 64 + j) * 8 + laneJ] = val + btv;
        } else if (laneJ == 8) {
          const float z = val + bcv;
          out[(size_t)CAU_OFF + (size_t)rowi * 64 + j] = m / (1.f + expf(-z));
        }
      }
    }
  }
}

// ---------------------------------------------------------------------------
extern "C" void kernel_launch(void* const* d_in, const int* in_sizes, int n_in,
                              void* d_out, int out_size, void* d_ws, size_t ws_size,
                              hipStream_t stream) {
  const float* slots     = (const float*)d_in[0];
  const float* positions = (const float*)d_in[1];
  const float* em        = (const float*)d_in[2];
  const float* W1        = (const float*)d_in[3];
  const float* b1        = (const float*)d_in[4];
  const float* W2        = (const float*)d_in[5];
  const float* b2        = (const float*)d_in[6];
  const float* Wt        = (const float*)d_in[7];
  const float* bt        = (const float*)d_in[8];
  const float* Wc        = (const float*)d_in[9];
  const float* bc        = (const float*)d_in[10];
  float* out = (float*)d_out;

  float* Abuf = (float*)d_ws;                   // [2048][256]  2MB
  float* Cbuf = Abuf + 524288;                  // [2048][256]  2MB
  float* b2e  = Cbuf + 524288;                  // [144] (pad to 256)
  short* WfHi = (short*)(b2e + 256);            // [72*64*8] bf16 bits
  short* WfLo = WfHi + 36864;

  prep_w <<<18,  256, 0, stream>>>(W2, b2, Wt, Wc, b2e, WfHi, WfLo);
  prep_ac<<<512, 256, 0, stream>>>(slots, W1, b1, Abuf, Cbuf);
  main_kernel<<<2048, 256, 0, stream>>>(positions, em, W1, Abuf, Cbuf,
                                        b2e, WfHi, WfLo, bt, bc, out);
}

// Round 5
// 173.316 us; speedup vs baseline: 1.9022x; 1.2775x over previous
//
#include <hip/hip_runtime.h>
#include <hip/hip_bf16.h>
#include <math.h>

// InteractionEncoder: B=32, N=64, D=256, ID=128, IN=516, H=256
// pair@W1 = A[b,i] + C[b,j] + geo(i,j)@W1[512:516]  (A,C precomputed, b1 folded)
// Layer 2 MFMA bf16 hi/lo (3-term): H[32x256] @ W2ext[256x144] per block,
// cols 128-135 = W2@Wt (itypes), 136 = W2@Wc (causal), 137-143 = 0.
// R4 (resubmit; prior round hit GPU-acquisition timeout): parallel Wtx,
// 512-thr prep_ac (k-split), 32-row main blocks (4 blocks/CU) +
// LDS-transposed vectorized stores.

typedef __attribute__((ext_vector_type(8))) short  bfrag8;  // 8 bf16 bits
typedef __attribute__((ext_vector_type(4))) short  spack4;  // 4 bf16 bits
typedef __attribute__((ext_vector_type(4))) float  fvec4;

#define ITY_OFF   16777216u   // 2048*64*128
#define CAU_OFF   17825792u   // + 2048*64*8

static __device__ __forceinline__ short f2bf(float f) {   // RNE f32->bf16 bits
  unsigned u = __float_as_uint(f);
  u = u + 0x7FFF + ((u >> 16) & 1);
  return (short)(u >> 16);
}
static __device__ __forceinline__ float bf2f(short s) {
  return __uint_as_float(((unsigned)(unsigned short)s) << 16);
}

// ---------------------------------------------------------------------------
// P0: Wtx[k][q] = (W2@Wt | W2@Wc) fully parallel; b2e = b2 | b2@Wt | b2@Wc | 0.
// 9 blocks (q) x 256 threads (k).
__global__ __launch_bounds__(256) void prep_wtx(
    const float* __restrict__ W2,   // [256][128]
    const float* __restrict__ b2,   // [128]
    const float* __restrict__ Wt,   // [128][8]
    const float* __restrict__ Wc,   // [128]
    float* __restrict__ Wtx,        // [256][16] (cols 0..8 used)
    float* __restrict__ b2e)        // [144]
{
  __shared__ float colv[128];
  __shared__ float red[4];
  const int q   = blockIdx.x;       // 0..8
  const int tid = threadIdx.x;      // k
  if (tid < 128) colv[tid] = (q < 8) ? Wt[tid * 8 + q] : Wc[tid];
  __syncthreads();

  float acc = 0.f;
  #pragma unroll 4
  for (int c = 0; c < 128; ++c)
    acc = fmaf(W2[tid * 128 + c], colv[c], acc);
  Wtx[tid * 16 + q] = acc;

  float p = (tid < 128) ? b2[tid] * colv[tid] : 0.f;
  #pragma unroll
  for (int m = 1; m < 64; m <<= 1) p += __shfl_xor(p, m, 64);
  if ((tid & 63) == 0) red[tid >> 6] = p;
  __syncthreads();
  if (tid == 0) b2e[128 + q] = red[0] + red[1] + red[2] + red[3];
  if (q == 0) {
    if (tid < 128) b2e[tid] = b2[tid];
    if (tid >= 137 && tid < 144) b2e[tid] = 0.f;
  }
}

// ---------------------------------------------------------------------------
// P1: pack W2ext as hi/lo bf16 B-fragments (16x16x32 layout).
// Fragment (ks,db): lane l holds k = ks*32+(l>>4)*8+e, d = db*16+(l&15).
__global__ __launch_bounds__(256) void prep_w(
    const float* __restrict__ W2,   // [256][128]
    const float* __restrict__ Wtx,  // [256][16]
    short* __restrict__ WfHi,       // [72][64][8]
    short* __restrict__ WfLo)
{
  const int tid  = threadIdx.x;
  const int tile = blockIdx.x * 4 + (tid >> 6);
  const int l    = tid & 63;
  const int ks   = tile / 9, db = tile - ks * 9;
  const int d    = db * 16 + (l & 15);
  const int k0   = ks * 32 + ((l >> 4) & 3) * 8;

  float v[8];
  if (d < 128) {
    #pragma unroll
    for (int e = 0; e < 8; ++e) v[e] = W2[(k0 + e) * 128 + d];
  } else if (d < 137) {
    #pragma unroll
    for (int e = 0; e < 8; ++e) v[e] = Wtx[(k0 + e) * 16 + (d - 128)];
  } else {
    #pragma unroll
    for (int e = 0; e < 8; ++e) v[e] = 0.f;
  }

  bfrag8 hi, lo;
  #pragma unroll
  for (int e = 0; e < 8; ++e) {
    const short hb = f2bf(v[e]);
    hi[e] = hb;
    lo[e] = f2bf(v[e] - bf2f(hb));
  }
  *(bfrag8*)&WfHi[(tile * 64 + l) * 8] = hi;
  *(bfrag8*)&WfLo[(tile * 64 + l) * 8] = lo;
}

// ---------------------------------------------------------------------------
// P2: A/C precompute. 512 blocks x 512 thr; 4 rows/block; k split in halves.
__global__ __launch_bounds__(512) void prep_ac(
    const float* __restrict__ slots,  // [2048][256]
    const float* __restrict__ W1,     // [516][256]
    const float* __restrict__ b1,     // [256]
    float* __restrict__ Abuf,         // [2048][256] = slots@W1[0:256] + b1
    float* __restrict__ Cbuf)         // [2048][256] = slots@W1[256:512]
{
  __shared__ __align__(16) float s[4][256];
  __shared__ float pA[4][256], pC[4][256];
  const int tid  = threadIdx.x;
  const int col  = tid & 255;
  const int kh   = tid >> 8;          // 0/1: k half
  const int row0 = blockIdx.x * 4;
  {
    const int r = tid >> 7, o = (tid & 127) * 2;
    *(float2*)&s[r][o] = *(const float2*)&slots[(row0 + r) * 256 + o];
  }
  __syncthreads();

  float aA[4] = {0.f,0.f,0.f,0.f};
  float aC[4] = {0.f,0.f,0.f,0.f};
  const int kbase = kh * 128;
  #pragma unroll 2
  for (int kk = 0; kk < 128; ++kk) {
    const int k = kbase + kk;
    const float wa = W1[k * 256 + col];
    const float wc = W1[(256 + k) * 256 + col];
    #pragma unroll
    for (int r = 0; r < 4; ++r) {
      aA[r] = fmaf(s[r][k], wa, aA[r]);
      aC[r] = fmaf(s[r][k], wc, aC[r]);
    }
  }
  if (kh == 1) {
    #pragma unroll
    for (int r = 0; r < 4; ++r) { pA[r][col] = aA[r]; pC[r][col] = aC[r]; }
  }
  __syncthreads();
  if (kh == 0) {
    const float bv = b1[col];
    #pragma unroll
    for (int r = 0; r < 4; ++r) {
      Abuf[(row0 + r) * 256 + col] = aA[r] + pA[r][col] + bv;
      Cbuf[(row0 + r) * 256 + col] = aC[r] + pC[r][col];
    }
  }
}

// ---------------------------------------------------------------------------
// Main: block = (b, i, jhalf): 32 j rows. LDS 33KB -> 4 blocks/CU.
__global__ __launch_bounds__(256, 4) void main_kernel(
    const float* __restrict__ positions, // [2048][4]
    const float* __restrict__ em,        // [2048]
    const float* __restrict__ W1,        // [516][256] (geo rows 512..515)
    const float* __restrict__ Abuf,
    const float* __restrict__ Cbuf,
    const float* __restrict__ b2e,       // [144]
    const short* __restrict__ WfHi,
    const short* __restrict__ WfLo,
    const float* __restrict__ bt,        // [8]
    const float* __restrict__ bc,        // [1]
    float* __restrict__ out)
{
  __shared__ __align__(16) char LDSbuf[32768];   // Hhi[16K] | Hlo[16K]; reused as FS
  __shared__ float maskL[32];

  const int tid = threadIdx.x;
  const int l   = tid & 63;
  const int w   = tid >> 6;
  // XCD swizzle: blocks sharing b stay on one XCD (Cbuf/Abuf slice L2 reuse)
  const int wid   = (blockIdx.x & 7) * 512 + (blockIdx.x >> 3);
  const int b     = wid >> 7;
  const int i     = (wid >> 1) & 63;
  const int jhalf = wid & 1;
  const int rowi  = b * 64 + i;
  const int j0    = jhalf * 32;

  if (tid < 32) maskL[tid] = em[rowi] * em[b * 64 + j0 + tid];

  char* HhiB = LDSbuf;
  char* HloB = LDSbuf + 16384;

  // ---- phase 1: build H[32][256] hi/lo. wave w: j = w*8 + jsub*2 + jj ----
  {
    const int jsub = l >> 4;
    const int kl4  = (l & 15) * 4;
    const float pxi = positions[rowi * 4 + 0];
    const float pyi = positions[rowi * 4 + 1];
    float grx[2], gry[2], gdn[2], gdc[2];
    #pragma unroll
    for (int jj = 0; jj < 2; ++jj) {
      const int rowj = b * 64 + j0 + w * 8 + jsub * 2 + jj;
      const float rx = pxi - positions[rowj * 4 + 0];
      const float ry = pyi - positions[rowj * 4 + 1];
      const float d2 = rx * rx + ry * ry;
      const float dist = (d2 == 0.f) ? 0.f : sqrtf(d2);
      const float dn = dist * (1.0f / 50.0f);
      grx[jj] = rx; gry[jj] = ry; gdn[jj] = dn; gdc[jj] = fminf(dn, 1.f);
    }
    #pragma unroll 1
    for (int kb = 0; kb < 4; ++kb) {
      const int k = kb * 64 + kl4;
      const fvec4 a4 = *(const fvec4*)&Abuf[rowi * 256 + k];
      const fvec4 g0 = *(const fvec4*)&W1[512 * 256 + k];
      const fvec4 g1 = *(const fvec4*)&W1[513 * 256 + k];
      const fvec4 g2 = *(const fvec4*)&W1[514 * 256 + k];
      const fvec4 g3 = *(const fvec4*)&W1[515 * 256 + k];
      #pragma unroll
      for (int jj = 0; jj < 2; ++jj) {
        const int j = w * 8 + jsub * 2 + jj;   // local 0..31
        const fvec4 c4 = *(const fvec4*)&Cbuf[(b * 64 + j0 + j) * 256 + k];
        spack4 hi, lo;
        #pragma unroll
        for (int e = 0; e < 4; ++e) {
          float h = a4[e] + c4[e] + grx[jj] * g0[e] + gry[jj] * g1[e]
                  + gdn[jj] * g2[e] + gdc[jj] * g3[e];
          h = fmaxf(h, 0.f);
          const short hb = f2bf(h);
          hi[e] = hb;
          lo[e] = f2bf(h - bf2f(hb));
        }
        const int byte = (j * 512 + k * 2) ^ ((j & 7) << 4);
        *(spack4*)(HhiB + byte) = hi;
        *(spack4*)(HloB + byte) = lo;
      }
    }
  }
  __syncthreads();

  // ---- phase 2: MFMA. w0:{0,1} w1:{2,3} w2:{4,5}+db8/jb0 w3:{6,7}+db8/jb1 ----
  const int laneJ = l & 15;
  const int laneK = l >> 4;
  const int addrA = laneJ * 512 + laneK * 16;
  const int swzA  = (laneJ & 7) << 4;

  fvec4 acc[2][2];   // [jb][t]
  fvec4 acc8;
  acc[0][0] = 0.f; acc[0][1] = 0.f; acc[1][0] = 0.f; acc[1][1] = 0.f;
  acc8 = 0.f;

  const int db0 = 2 * w, db1 = 2 * w + 1;
  const bool has8 = (w >= 2);
  const int jb8 = w - 2;

  #pragma unroll
  for (int ks = 0; ks < 8; ++ks) {
    const bfrag8 bh0 = *(const bfrag8*)&WfHi[((ks * 9 + db0) * 64 + l) * 8];
    const bfrag8 bl0 = *(const bfrag8*)&WfLo[((ks * 9 + db0) * 64 + l) * 8];
    const bfrag8 bh1 = *(const bfrag8*)&WfHi[((ks * 9 + db1) * 64 + l) * 8];
    const bfrag8 bl1 = *(const bfrag8*)&WfLo[((ks * 9 + db1) * 64 + l) * 8];
    bfrag8 bh8 = {}, bl8 = {};
    if (has8) {
      bh8 = *(const bfrag8*)&WfHi[((ks * 9 + 8) * 64 + l) * 8];
      bl8 = *(const bfrag8*)&WfLo[((ks * 9 + 8) * 64 + l) * 8];
    }
    #pragma unroll
    for (int jb = 0; jb < 2; ++jb) {
      const int base = addrA + jb * 8192 + ks * 64;
      const bfrag8 ah = *(const bfrag8*)(HhiB + (base ^ swzA));
      const bfrag8 al = *(const bfrag8*)(HloB + (base ^ swzA));
      acc[jb][0] = __builtin_amdgcn_mfma_f32_16x16x32_bf16(ah, bh0, acc[jb][0], 0, 0, 0);
      acc[jb][0] = __builtin_amdgcn_mfma_f32_16x16x32_bf16(ah, bl0, acc[jb][0], 0, 0, 0);
      acc[jb][0] = __builtin_amdgcn_mfma_f32_16x16x32_bf16(al, bh0, acc[jb][0], 0, 0, 0);
      acc[jb][1] = __builtin_amdgcn_mfma_f32_16x16x32_bf16(ah, bh1, acc[jb][1], 0, 0, 0);
      acc[jb][1] = __builtin_amdgcn_mfma_f32_16x16x32_bf16(ah, bl1, acc[jb][1], 0, 0, 0);
      acc[jb][1] = __builtin_amdgcn_mfma_f32_16x16x32_bf16(al, bh1, acc[jb][1], 0, 0, 0);
      if (has8 && jb == jb8) {
        acc8 = __builtin_amdgcn_mfma_f32_16x16x32_bf16(ah, bh8, acc8, 0, 0, 0);
        acc8 = __builtin_amdgcn_mfma_f32_16x16x32_bf16(ah, bl8, acc8, 0, 0, 0);
        acc8 = __builtin_amdgcn_mfma_f32_16x16x32_bf16(al, bh8, acc8, 0, 0, 0);
      }
    }
  }

  __syncthreads();   // done reading H; LDS becomes FS[32][148]

  // ---- phase 3: bias+mask -> FS, then vectorized stores ----
  float* FS = (float*)LDSbuf;
  #pragma unroll
  for (int t = 0; t < 2; ++t) {
    const int d = (2 * w + t) * 16 + laneJ;
    const float bv = b2e[d];
    #pragma unroll
    for (int jb = 0; jb < 2; ++jb) {
      #pragma unroll
      for (int r = 0; r < 4; ++r) {
        const int j = jb * 16 + laneK * 4 + r;
        FS[j * 148 + d] = (acc[jb][t][r] + bv) * maskL[j];
      }
    }
  }
  if (has8) {
    const int d8 = 128 + laneJ;
    const float bv = b2e[d8];
    #pragma unroll
    for (int r = 0; r < 4; ++r) {
      const int j = jb8 * 16 + laneK * 4 + r;
      FS[j * 148 + d8] = (acc8[r] + bv) * maskL[j];
    }
  }
  __syncthreads();

  {
    const int j  = tid >> 3;          // 0..31
    const int dq = (tid & 7) * 16;    // d base
    const size_t orow = ((size_t)rowi * 64 + j0 + j) * 128;
    #pragma unroll
    for (int q = 0; q < 4; ++q) {
      const fvec4 v = *(const fvec4*)&FS[j * 148 + dq + q * 4];
      *(fvec4*)&out[orow + dq + q * 4] = v;
    }
    // itypes
    const int q8 = tid & 7;
    out[(size_t)ITY_OFF + ((size_t)rowi * 64 + j0 + j) * 8 + q8] =
        FS[j * 148 + 128 + q8] + bt[q8];
    // causal
    if (tid < 32) {
      const float z = FS[tid * 148 + 136] + bc[0];
      out[(size_t)CAU_OFF + (size_t)rowi * 64 + j0 + tid] =
          maskL[tid] / (1.f + expf(-z));
    }
  }
}

// ---------------------------------------------------------------------------
extern "C" void kernel_launch(void* const* d_in, const int* in_sizes, int n_in,
                              void* d_out, int out_size, void* d_ws, size_t ws_size,
                              hipStream_t stream) {
  const float* slots     = (const float*)d_in[0];
  const float* positions = (const float*)d_in[1];
  const float* em        = (const float*)d_in[2];
  const float* W1        = (const float*)d_in[3];
  const float* b1        = (const float*)d_in[4];
  const float* W2        = (const float*)d_in[5];
  const float* b2        = (const float*)d_in[6];
  const float* Wt        = (const float*)d_in[7];
  const float* bt        = (const float*)d_in[8];
  const float* Wc        = (const float*)d_in[9];
  const float* bc        = (const float*)d_in[10];
  float* out = (float*)d_out;

  float* Abuf = (float*)d_ws;                   // [2048][256]
  float* Cbuf = Abuf + 524288;                  // [2048][256]
  float* b2e  = Cbuf + 524288;                  // [144] pad 256
  float* Wtx  = b2e + 256;                      // [256][16]
  short* WfHi = (short*)(Wtx + 4096);           // [72*64*8]
  short* WfLo = WfHi + 36864;

  prep_wtx<<<9,   256, 0, stream>>>(W2, b2, Wt, Wc, Wtx, b2e);
  prep_w  <<<18,  256, 0, stream>>>(W2, Wtx, WfHi, WfLo);
  prep_ac <<<512, 512, 0, stream>>>(slots, W1, b1, Abuf, Cbuf);
  main_kernel<<<4096, 256, 0, stream>>>(positions, em, W1, Abuf, Cbuf,
                                        b2e, WfHi, WfLo, bt, bc, out);
}